// Round 12
// baseline (473.591 us; speedup 1.0000x reference)
//
#include <hip/hip_runtime.h>
#include <hip/hip_bf16.h>
#include <hip/hip_fp16.h>

// Problem constants (match reference)
static constexpr int CH     = 128;   // IN_CH == HID
static constexpr int NCLS   = 32;
static constexpr int NGRAPH = 256;

// Bucketed CSR build: buckets are 512-node ranges (bucket = dst >> 9).
static constexpr int BSHIFT = 9;
static constexpr int BW     = 1 << BSHIFT;   // 512 nodes per bucket
static constexpr int MAXB   = 256;

typedef _Float16 half8 __attribute__((ext_vector_type(8)));
typedef _Float16 half4 __attribute__((ext_vector_type(4)));
typedef float    f32x4 __attribute__((ext_vector_type(4)));

// ---------------------------------------------------------------------------
// 1) init: block 0 sets bucket cursors to b*CAP (over-allocated regions;
//    no histogram/scan needed). blocks 1..128: W1,W2 -> fp16 transpose.
// ---------------------------------------------------------------------------
__global__ __launch_bounds__(256) void k_init_wt(
    int* __restrict__ gcur, int CAP, int NBUCK,
    const float* __restrict__ W1, const float* __restrict__ W2,
    _Float16* __restrict__ WhT1, _Float16* __restrict__ WhT2) {
  int t = threadIdx.x;
  if (blockIdx.x == 0) {
    if (t < NBUCK) gcur[t] = t * CAP;
    return;
  }
  int i = (blockIdx.x - 1) * 256 + t;       // 0..32767
  const float* W = (i < CH * CH) ? W1 : W2;
  _Float16* T   = (i < CH * CH) ? WhT1 : WhT2;
  int j = i & (CH * CH - 1);
  int k = j >> 7, n = j & 127;
  T[n * CH + k] = (_Float16)W[j];
}

// ---------------------------------------------------------------------------
// 2) scatter packed edges into over-allocated bucket regions.
//    pack = (dstlo << 17) | src   (dstlo < 512 -> 9 bits; src < 2^17)
// ---------------------------------------------------------------------------
__global__ __launch_bounds__(1024) void k_scatter(
    const int* __restrict__ src, const int* __restrict__ dst,
    int* __restrict__ gcur, int* __restrict__ ebuf, int E) {
  __shared__ int bcnt[MAXB];
  __shared__ int bbase[MAXB];
  int t = threadIdx.x;
  if (t < MAXB) bcnt[t] = 0;
  __syncthreads();
  int base = blockIdx.x * 8192;
  int s_[8], d_[8], r_[8];
  #pragma unroll
  for (int j = 0; j < 8; ++j) {
    int i = base + j * 1024 + t;
    if (i < E) {
      s_[j] = src[i];
      d_[j] = dst[i];
      r_[j] = atomicAdd(&bcnt[d_[j] >> BSHIFT], 1);
    }
  }
  __syncthreads();
  if (t < MAXB && bcnt[t]) bbase[t] = atomicAdd(&gcur[t], bcnt[t]);
  __syncthreads();
  #pragma unroll
  for (int j = 0; j < 8; ++j) {
    int i = base + j * 1024 + t;
    if (i < E) {
      int b = d_[j] >> BSHIFT;
      int p = ((d_[j] & (BW - 1)) << 17) | s_[j];
      ebuf[bbase[b] + r_[j]] = p;
    }
  }
}

// ---------------------------------------------------------------------------
// 3) FUSED: blocks [0, GB64) = GEMM layer-1 (x fp32 @ W1 -> xs fp16,
//    UNscaled — dinv applied per-edge in agg); blocks [GB64, GB64+NBUCK) =
//    per-bucket CSR build. Both 256 threads; shared memory union.
//    Overlaps gemm streaming with build's atomic/barrier latency.
// ---------------------------------------------------------------------------
__device__ __forceinline__ void stage_w(const _Float16* __restrict__ WhT,
                                        _Float16 (*Ws)[136], int tid) {
  #pragma unroll
  for (int l = 0; l < 8; ++l) {
    int idx = tid + l * 256;            // 0..2047 half8 chunks
    int n = idx >> 4, k8 = (idx & 15) << 3;
    *(half8*)&Ws[n][k8] = *(const half8*)(WhT + n * CH + k8);
  }
}

__device__ __forceinline__ void gemm_core64(
    const _Float16 (*As)[136], const _Float16 (*Ws)[136],
    __half* __restrict__ C, int row0, int M, int tid) {
  int lane = tid & 63, wave = tid >> 6;
  int quad = lane >> 4, sub = lane & 15;
  int m0 = wave * 16;

  f32x4 acc[8];
  #pragma unroll
  for (int j = 0; j < 8; ++j) acc[j] = (f32x4){0.f, 0.f, 0.f, 0.f};

  #pragma unroll
  for (int kc = 0; kc < 4; ++kc) {
    int ko = kc * 32 + quad * 8;
    half8 a = *(const half8*)&As[m0 + sub][ko];
    #pragma unroll
    for (int nt = 0; nt < 8; ++nt) {
      half8 b = *(const half8*)&Ws[nt * 16 + sub][ko];
      acc[nt] = __builtin_amdgcn_mfma_f32_16x16x32_f16(a, b, acc[nt], 0, 0, 0);
    }
  }
  #pragma unroll
  for (int r = 0; r < 4; ++r) {
    int row = row0 + m0 + quad * 4 + r;
    if (row < M) {
      #pragma unroll
      for (int nt = 0; nt < 8; ++nt)
        C[(size_t)row * CH + nt * 16 + sub] = __float2half(acc[nt][r]);
    }
  }
}

__global__ __launch_bounds__(256) void k_gemm1_build(
    const float* __restrict__ A, const _Float16* __restrict__ WhT,
    __half* __restrict__ C,
    const int* __restrict__ ebuf, const int* __restrict__ gcur,
    int* __restrict__ offs, int* __restrict__ oend,
    float* __restrict__ dinv, int* __restrict__ csr,
    int N, int CAP, int GB64) {
  __shared__ __align__(16) char smem[52224];
  int tid = threadIdx.x;

  if ((int)blockIdx.x < GB64) {
    // ---- GEMM layer 1 ----
    _Float16 (*As)[136] = (_Float16(*)[136])smem;
    _Float16 (*Ws)[136] = (_Float16(*)[136])(smem + 64 * 136 * 2);
    int row0 = blockIdx.x * 64;
    #pragma unroll
    for (int l = 0; l < 8; ++l) {
      int idx = tid + l * 256;
      int r = idx >> 5, c4 = (idx & 31) << 2;
      int rr = row0 + r; if (rr >= N) rr = N - 1;
      float4 v = *(const float4*)(A + (size_t)rr * CH + c4);
      half4 hv = { (_Float16)v.x, (_Float16)v.y, (_Float16)v.z, (_Float16)v.w };
      *(half4*)&As[r][c4] = hv;
    }
    stage_w(WhT, Ws, tid);
    __syncthreads();
    gemm_core64(As, Ws, C, row0, N, tid);
    return;
  }

  // ---- CSR build for bucket b ----
  int b = blockIdx.x - GB64;
  int* sdeg  = (int*)smem;         // 512
  int* sscan = sdeg + BW;          // 512
  int lo = b << BSHIFT;
  int e0 = b * CAP;
  int e1 = gcur[b];                // = b*CAP + count after scatter

  sdeg[tid] = 0; sdeg[tid + 256] = 0;
  __syncthreads();
  for (int e = e0 + tid; e < e1; e += 256)
    atomicAdd(&sdeg[ebuf[e] >> 17], 1);
  __syncthreads();
  sscan[tid] = sdeg[tid]; sscan[tid + 256] = sdeg[tid + 256];
  __syncthreads();
  for (int st = 1; st < BW; st <<= 1) {
    int va = (tid >= st) ? sscan[tid - st] : 0;
    int vb = sscan[tid + 256 - st];
    __syncthreads();
    sscan[tid] += va; sscan[tid + 256] += vb;
    __syncthreads();
  }
  #pragma unroll
  for (int h = 0; h < 2; ++h) {
    int i = tid + h * 256;
    int ex = b * CAP + sscan[i] - sdeg[i];   // csr offset (gapped layout)
    int n = lo + i;
    if (n < N) {
      offs[n] = ex;
      oend[n] = ex + sdeg[i];
      dinv[n] = 1.0f / sqrtf((float)(sdeg[i] + 1));
    }
  }
  __syncthreads();
  #pragma unroll
  for (int h = 0; h < 2; ++h) {
    int i = tid + h * 256;
    sscan[i] = b * CAP + sscan[i] - sdeg[i]; // fill cursor
  }
  __syncthreads();
  for (int e = e0 + tid; e < e1; e += 256) {
    int p = ebuf[e];
    int pos = atomicAdd(&sscan[p >> 17], 1);
    csr[pos] = p & 0x1FFFF;
  }
}

// Plain GEMM (layer 2, fp16 input, unscaled output)
__global__ __launch_bounds__(256) void k_gemm_f16(
    const _Float16* __restrict__ A, const _Float16* __restrict__ WhT,
    __half* __restrict__ C, int M) {
  __shared__ _Float16 As[64][136];
  __shared__ _Float16 Ws[128][136];
  int tid = threadIdx.x;
  int row0 = blockIdx.x * 64;
  #pragma unroll
  for (int l = 0; l < 4; ++l) {
    int idx = tid + l * 256;
    int r = idx >> 4, c8 = (idx & 15) << 3;
    int rr = row0 + r; if (rr >= M) rr = M - 1;
    *(half8*)&As[r][c8] = *(const half8*)(A + (size_t)rr * CH + c8);
  }
  stage_w(WhT, Ws, tid);
  __syncthreads();
  gemm_core64(As, Ws, C, row0, M, tid);
}

// ---------------------------------------------------------------------------
// Aggregation (pull, CSR): out = fp16(relu((sum dinv[s]*xs[s] +
// dinv[n]*xs[n]) * dinv[n] + b)). xs unscaled fp16; dinv gathered per edge
// (lane-uniform, L2-hot). Unroll 8 + tail.
// ---------------------------------------------------------------------------
__global__ __launch_bounds__(256) void k_agg(
    const __half* __restrict__ xs, const int* __restrict__ csr,
    const int* __restrict__ offs, const int* __restrict__ oend,
    const float* __restrict__ dinv, const float* __restrict__ bias,
    __half* __restrict__ out, int N) {
  int node = blockIdx.x * 4 + (threadIdx.x >> 6);
  int lane = threadIdx.x & 63;
  if (node >= N) return;
  int beg = offs[node], end = oend[node];
  const __half2* base = (const __half2*)xs;
  float dn = dinv[node];
  float2 self = __half22float2(base[(size_t)node * 64 + lane]);
  float ax = self.x * dn, ay = self.y * dn;
  float bx = 0.f, by = 0.f;
  int e = beg;
  for (; e + 7 < end; e += 8) {
    int s[8];
    #pragma unroll
    for (int j = 0; j < 8; ++j) s[j] = csr[e + j];
    float2 v[8];
    float ds[8];
    #pragma unroll
    for (int j = 0; j < 8; ++j) {
      v[j]  = __half22float2(base[(size_t)s[j] * 64 + lane]);
      ds[j] = dinv[s[j]];
    }
    #pragma unroll
    for (int j = 0; j < 8; j += 4) {
      ax = fmaf(v[j].x, ds[j], ax);      ay = fmaf(v[j].y, ds[j], ay);
      bx = fmaf(v[j + 1].x, ds[j + 1], bx); by = fmaf(v[j + 1].y, ds[j + 1], by);
      ax = fmaf(v[j + 2].x, ds[j + 2], ax); ay = fmaf(v[j + 2].y, ds[j + 2], ay);
      bx = fmaf(v[j + 3].x, ds[j + 3], bx); by = fmaf(v[j + 3].y, ds[j + 3], by);
    }
  }
  for (; e < end; ++e) {
    int s = csr[e];
    float dsv = dinv[s];
    float2 v = __half22float2(base[(size_t)s * 64 + lane]);
    ax = fmaf(v.x, dsv, ax); ay = fmaf(v.y, dsv, ay);
  }
  ax += bx; ay += by;
  float rx = fmaf(ax, dn, bias[2 * lane]);
  float ry = fmaf(ay, dn, bias[2 * lane + 1]);
  ((__half2*)out)[(size_t)node * 64 + lane] =
      __floats2half2_rn(fmaxf(rx, 0.f), fmaxf(ry, 0.f));
}

// ---------------------------------------------------------------------------
// Pool + graph boundaries (batch sorted)
// ---------------------------------------------------------------------------
__global__ __launch_bounds__(128) void k_pool(
    const __half* __restrict__ h, const int* __restrict__ batch,
    float* __restrict__ gsum, int* __restrict__ gstart,
    int* __restrict__ gend, int N) {
  int ch = threadIdx.x;
  int n0 = blockIdx.x * 128;
  int n1 = n0 + 128; if (n1 > N) n1 = N;
  if (n0 >= N) return;
  for (int n = n0 + ch; n < n1; n += 128) {
    int g = batch[n];
    if (n == 0 || batch[n - 1] != g) gstart[g] = n;
    if (n == N - 1 || batch[n + 1] != g) gend[g] = n + 1;
  }
  float acc = 0.f;
  int curg = batch[n0];
  for (int n = n0; n < n1; ++n) {
    int g = batch[n];
    if (g != curg) {
      atomicAdd(&gsum[curg * CH + ch], acc);
      acc = 0.f; curg = g;
    }
    acc += __half2float(h[(size_t)n * CH + ch]);
  }
  atomicAdd(&gsum[curg * CH + ch], acc);
}

// ---------------------------------------------------------------------------
// FC
// ---------------------------------------------------------------------------
__global__ __launch_bounds__(64) void k_fc(
    const float* __restrict__ gsum, const int* __restrict__ gstart,
    const int* __restrict__ gend, const float* __restrict__ Wfc,
    const float* __restrict__ bfc, float* __restrict__ outp) {
  int g = blockIdx.x;
  int j = threadIdx.x;
  if (j >= NCLS) return;
  int cnt = gend[g] - gstart[g];
  float invc = 1.0f / fmaxf((float)cnt, 1.0f);
  float acc = 0.0f;
  for (int c = 0; c < CH; ++c)
    acc = fmaf(gsum[g * CH + c], Wfc[c * NCLS + j], acc);
  outp[g * NCLS + j] = fmaf(acc, invc, bfc[j]);
}

// ---------------------------------------------------------------------------
extern "C" void kernel_launch(void* const* d_in, const int* in_sizes, int n_in,
                              void* d_out, int out_size, void* d_ws, size_t ws_size,
                              hipStream_t stream) {
  const float* x    = (const float*)d_in[0];
  const int*   ei   = (const int*)d_in[1];
  const int*   batch= (const int*)d_in[2];
  const float* W1   = (const float*)d_in[3];
  const float* b1   = (const float*)d_in[4];
  const float* W2   = (const float*)d_in[5];
  const float* b2   = (const float*)d_in[6];
  const float* Wfc  = (const float*)d_in[7];
  const float* bfc  = (const float*)d_in[8];
  float* outp = (float*)d_out;

  const int N = in_sizes[0] / CH;       // 100000
  const int E = in_sizes[1] / 2;        // 3200000
  const int* src = ei;
  const int* dst = ei + E;
  const int NBUCK = (N + BW - 1) >> BSHIFT;   // 196
  // Over-allocated bucket capacity: mean + ~18 sigma (Binomial), fill-safe.
  const int CAP = (E / NBUCK) + (E / NBUCK) / 8 + 256;

  // Workspace carve (256B aligned). First three buffers zeroed by ONE memset.
  char* w = (char*)d_ws;
  size_t o = 0;
  auto carve = [&](size_t bytes) -> void* {
    o = (o + 255) & ~(size_t)255;
    void* p = w + o;
    o += bytes;
    return p;
  };
  float*    gsum   = (float*)   carve((size_t)NGRAPH * CH * 4);  // zeroed
  int*      gstart = (int*)     carve((size_t)NGRAPH * 4);       // zeroed
  int*      gend   = (int*)     carve((size_t)NGRAPH * 4);       // zeroed
  size_t zbytes = o;
  int*      offs   = (int*)     carve((size_t)N * 4);
  int*      oendb  = (int*)     carve((size_t)N * 4);
  int*      gcur   = (int*)     carve(MAXB * 4);
  int*      csr    = (int*)     carve((size_t)NBUCK * CAP * 4);
  float*    dinv   = (float*)   carve((size_t)N * 4);
  _Float16* WhT1   = (_Float16*)carve((size_t)CH * CH * 2);
  _Float16* WhT2   = (_Float16*)carve((size_t)CH * CH * 2);
  __half*   xsbuf  = (__half*)  carve((size_t)N * CH * 2);  // fp16 gather buffer
  __half*   hbuf   = (__half*)  carve((size_t)N * CH * 2);  // fp16 h
  (void)ws_size;

  // ebuf (packed edges, gapped) aliases hbuf: NBUCK*CAP*4 ~ 14.7MB <= 25.6MB
  int* ebuf = (int*)hbuf;

  (void)hipMemsetAsync(gsum, 0, zbytes, stream);

  const int GB64 = (N + 63) / 64;       // 1563
  const int GB   = (N + 127) / 128;
  const int AB   = (N + 3) / 4;

  k_init_wt<<<129, 256, 0, stream>>>(gcur, CAP, NBUCK, W1, W2, WhT1, WhT2);
  k_scatter<<<(E + 8191) / 8192, 1024, 0, stream>>>(src, dst, gcur, ebuf, E);
  // fused: gemm layer-1 (blocks 0..GB64) + CSR build (blocks GB64..GB64+NBUCK)
  k_gemm1_build<<<GB64 + NBUCK, 256, 0, stream>>>(
      x, WhT1, xsbuf, ebuf, gcur, offs, oendb, dinv, csr, N, CAP, GB64);
  k_agg<<<AB, 256, 0, stream>>>(xsbuf, csr, offs, oendb, dinv, b1, hbuf, N);
  k_gemm_f16<<<GB64, 256, 0, stream>>>((const _Float16*)hbuf, WhT2, xsbuf, N);
  k_agg<<<AB, 256, 0, stream>>>(xsbuf, csr, offs, oendb, dinv, b2, hbuf, N);
  k_pool<<<GB, 128, 0, stream>>>(hbuf, batch, gsum, gstart, gend, N);
  k_fc<<<NGRAPH, 64, 0, stream>>>(gsum, gstart, gend, Wfc, bfc, outp);
  (void)out_size; (void)n_in;
}

// Round 13
// 450.443 us; speedup vs baseline: 1.0514x; 1.0514x over previous
//
#include <hip/hip_runtime.h>
#include <hip/hip_bf16.h>
#include <hip/hip_fp16.h>

// Problem constants (match reference)
static constexpr int CH     = 128;   // IN_CH == HID
static constexpr int NCLS   = 32;
static constexpr int NGRAPH = 256;

// Bucketed CSR build: buckets are 512-node ranges (bucket = dst >> 9).
static constexpr int BSHIFT = 9;
static constexpr int BW     = 1 << BSHIFT;   // 512 nodes per bucket
static constexpr int MAXB   = 256;

typedef _Float16 half8 __attribute__((ext_vector_type(8)));
typedef _Float16 half4 __attribute__((ext_vector_type(4)));
typedef float    f32x4 __attribute__((ext_vector_type(4)));

// ---------------------------------------------------------------------------
// 1) init: block 0 sets bucket cursors to b*CAP (over-allocated regions;
//    no histogram/scan needed). blocks 1..128: W1,W2 -> fp16 transpose.
// ---------------------------------------------------------------------------
__global__ __launch_bounds__(256) void k_init_wt(
    int* __restrict__ gcur, int CAP, int NBUCK,
    const float* __restrict__ W1, const float* __restrict__ W2,
    _Float16* __restrict__ WhT1, _Float16* __restrict__ WhT2) {
  int t = threadIdx.x;
  if (blockIdx.x == 0) {
    if (t < NBUCK) gcur[t] = t * CAP;
    return;
  }
  int i = (blockIdx.x - 1) * 256 + t;       // 0..32767
  const float* W = (i < CH * CH) ? W1 : W2;
  _Float16* T   = (i < CH * CH) ? WhT1 : WhT2;
  int j = i & (CH * CH - 1);
  int k = j >> 7, n = j & 127;
  T[n * CH + k] = (_Float16)W[j];
}

// ---------------------------------------------------------------------------
// 2) scatter packed edges into over-allocated bucket regions.
//    pack = (dstlo << 17) | src   (dstlo < 512 -> 9 bits; src < 2^17)
// ---------------------------------------------------------------------------
__global__ __launch_bounds__(1024) void k_scatter(
    const int* __restrict__ src, const int* __restrict__ dst,
    int* __restrict__ gcur, int* __restrict__ ebuf, int E) {
  __shared__ int bcnt[MAXB];
  __shared__ int bbase[MAXB];
  int t = threadIdx.x;
  if (t < MAXB) bcnt[t] = 0;
  __syncthreads();
  int base = blockIdx.x * 8192;
  int s_[8], d_[8], r_[8];
  #pragma unroll
  for (int j = 0; j < 8; ++j) {
    int i = base + j * 1024 + t;
    if (i < E) {
      s_[j] = src[i];
      d_[j] = dst[i];
      r_[j] = atomicAdd(&bcnt[d_[j] >> BSHIFT], 1);
    }
  }
  __syncthreads();
  if (t < MAXB && bcnt[t]) bbase[t] = atomicAdd(&gcur[t], bcnt[t]);
  __syncthreads();
  #pragma unroll
  for (int j = 0; j < 8; ++j) {
    int i = base + j * 1024 + t;
    if (i < E) {
      int b = d_[j] >> BSHIFT;
      int p = ((d_[j] & (BW - 1)) << 17) | s_[j];
      ebuf[bbase[b] + r_[j]] = p;
    }
  }
}

// ---------------------------------------------------------------------------
// 3) per-bucket CSR build (packed edges, gapped CAP regions).
//    Writes offs/oend (gapped layout), dinv, csr.
// ---------------------------------------------------------------------------
__global__ __launch_bounds__(1024) void k_build(
    const int* __restrict__ ebuf, const int* __restrict__ gcur,
    int* __restrict__ offs, int* __restrict__ oend,
    float* __restrict__ dinv, int* __restrict__ csr, int N, int CAP) {
  __shared__ int sdeg[BW];
  __shared__ int sscan[BW];
  int b = blockIdx.x;
  int t = threadIdx.x;
  int lo = b << BSHIFT;
  int e0 = b * CAP;
  int e1 = gcur[b];                  // b*CAP + bucket count after scatter

  if (t < BW) sdeg[t] = 0;
  __syncthreads();
  for (int e = e0 + t; e < e1; e += 1024)
    atomicAdd(&sdeg[ebuf[e] >> 17], 1);
  __syncthreads();
  if (t < BW) sscan[t] = sdeg[t];
  __syncthreads();
  for (int st = 1; st < BW; st <<= 1) {
    int v = (t < BW && t >= st) ? sscan[t - st] : 0;
    __syncthreads();
    if (t < BW) sscan[t] += v;
    __syncthreads();
  }
  if (t < BW) {
    int ex = b * CAP + sscan[t] - sdeg[t];   // gapped csr offset
    int n = lo + t;
    if (n < N) {
      offs[n] = ex;
      oend[n] = ex + sdeg[t];
      dinv[n] = 1.0f / sqrtf((float)(sdeg[t] + 1));
    }
    sscan[t] = ex;                            // fill cursor
  }
  __syncthreads();
  for (int e = e0 + t; e < e1; e += 1024) {
    int p = ebuf[e];
    int pos = atomicAdd(&sscan[p >> 17], 1);
    csr[pos] = p & 0x1FFFF;
  }
}

// ---------------------------------------------------------------------------
// MFMA GEMM: 64-row tiles, 4 waves x 16 rows, K=128 single shot, epilogue
// scales by dinv -> fp16 (scaled-xs form: dinv cost is per-node, not
// per-edge). As 17.4KB + Ws 34.8KB = 52.2KB LDS -> 3 blocks/CU.
// ---------------------------------------------------------------------------
__device__ __forceinline__ void stage_w(const _Float16* __restrict__ WhT,
                                        _Float16 (*Ws)[136], int tid) {
  #pragma unroll
  for (int l = 0; l < 8; ++l) {
    int idx = tid + l * 256;            // 0..2047 half8 chunks
    int n = idx >> 4, k8 = (idx & 15) << 3;
    *(half8*)&Ws[n][k8] = *(const half8*)(WhT + n * CH + k8);
  }
}

__device__ __forceinline__ void gemm_core64(
    const _Float16 (*As)[136], const _Float16 (*Ws)[136],
    const float* __restrict__ dinv, __half* __restrict__ C,
    int row0, int M, int tid) {
  int lane = tid & 63, wave = tid >> 6;
  int quad = lane >> 4, sub = lane & 15;
  int m0 = wave * 16;

  f32x4 acc[8];
  #pragma unroll
  for (int j = 0; j < 8; ++j) acc[j] = (f32x4){0.f, 0.f, 0.f, 0.f};

  #pragma unroll
  for (int kc = 0; kc < 4; ++kc) {
    int ko = kc * 32 + quad * 8;
    half8 a = *(const half8*)&As[m0 + sub][ko];
    #pragma unroll
    for (int nt = 0; nt < 8; ++nt) {
      half8 b = *(const half8*)&Ws[nt * 16 + sub][ko];
      acc[nt] = __builtin_amdgcn_mfma_f32_16x16x32_f16(a, b, acc[nt], 0, 0, 0);
    }
  }
  #pragma unroll
  for (int r = 0; r < 4; ++r) {
    int row = row0 + m0 + quad * 4 + r;
    if (row < M) {
      float d = dinv[row];
      #pragma unroll
      for (int nt = 0; nt < 8; ++nt)
        C[(size_t)row * CH + nt * 16 + sub] = __float2half(acc[nt][r] * d);
    }
  }
}

// A input fp32 (layer 1: x), packed half4 LDS stores
__global__ __launch_bounds__(256) void k_gemm_f32(
    const float* __restrict__ A, const _Float16* __restrict__ WhT,
    const float* __restrict__ dinv, __half* __restrict__ C, int M) {
  __shared__ _Float16 As[64][136];
  __shared__ _Float16 Ws[128][136];
  int tid = threadIdx.x;
  int row0 = blockIdx.x * 64;
  #pragma unroll
  for (int l = 0; l < 8; ++l) {
    int idx = tid + l * 256;
    int r = idx >> 5, c4 = (idx & 31) << 2;
    int rr = row0 + r; if (rr >= M) rr = M - 1;
    float4 v = *(const float4*)(A + (size_t)rr * CH + c4);
    half4 hv = { (_Float16)v.x, (_Float16)v.y, (_Float16)v.z, (_Float16)v.w };
    *(half4*)&As[r][c4] = hv;
  }
  stage_w(WhT, Ws, tid);
  __syncthreads();
  gemm_core64(As, Ws, dinv, C, row0, M, tid);
}

// A input fp16 (layer 2: h)
__global__ __launch_bounds__(256) void k_gemm_f16(
    const _Float16* __restrict__ A, const _Float16* __restrict__ WhT,
    const float* __restrict__ dinv, __half* __restrict__ C, int M) {
  __shared__ _Float16 As[64][136];
  __shared__ _Float16 Ws[128][136];
  int tid = threadIdx.x;
  int row0 = blockIdx.x * 64;
  #pragma unroll
  for (int l = 0; l < 4; ++l) {
    int idx = tid + l * 256;
    int r = idx >> 4, c8 = (idx & 15) << 3;
    int rr = row0 + r; if (rr >= M) rr = M - 1;
    *(half8*)&As[r][c8] = *(const half8*)(A + (size_t)rr * CH + c8);
  }
  stage_w(WhT, Ws, tid);
  __syncthreads();
  gemm_core64(As, Ws, dinv, C, row0, M, tid);
}

// ---------------------------------------------------------------------------
// Aggregation (pull, CSR): xs pre-scaled fp16. TWO nodes per wave processed
// in lockstep (8 independent gathers in flight) to probe request-parallelism
// headroom on the scattered-HBM path; per-node tails drain at 8/1.
// ---------------------------------------------------------------------------
__global__ __launch_bounds__(256) void k_agg(
    const __half* __restrict__ xs, const int* __restrict__ csr,
    const int* __restrict__ offs, const int* __restrict__ oend,
    const float* __restrict__ dinv, const float* __restrict__ bias,
    __half* __restrict__ out, int N) {
  int wid  = blockIdx.x * 4 + (threadIdx.x >> 6);
  int lane = threadIdx.x & 63;
  int nA = wid * 2, nB = nA + 1;
  if (nA >= N) return;
  bool hasB = (nB < N);
  const __half2* base = (const __half2*)xs;

  int eA = offs[nA], endA = oend[nA];
  int eB = hasB ? offs[nB] : 0;
  int endB = hasB ? oend[nB] : 0;

  float2 sfA = __half22float2(base[(size_t)nA * 64 + lane]);
  float axA = sfA.x, ayA = sfA.y, bxA = 0.f, byA = 0.f;
  float axB = 0.f, ayB = 0.f, bxB = 0.f, byB = 0.f;
  if (hasB) {
    float2 sfB = __half22float2(base[(size_t)nB * 64 + lane]);
    axB = sfB.x; ayB = sfB.y;
  }

  // lockstep: 4 edges of A + 4 edges of B per iteration (8 gathers in flight)
  while (eA + 3 < endA && eB + 3 < endB) {
    int a0 = csr[eA], a1 = csr[eA + 1], a2 = csr[eA + 2], a3 = csr[eA + 3];
    int b0 = csr[eB], b1 = csr[eB + 1], b2 = csr[eB + 2], b3 = csr[eB + 3];
    float2 vA0 = __half22float2(base[(size_t)a0 * 64 + lane]);
    float2 vA1 = __half22float2(base[(size_t)a1 * 64 + lane]);
    float2 vA2 = __half22float2(base[(size_t)a2 * 64 + lane]);
    float2 vA3 = __half22float2(base[(size_t)a3 * 64 + lane]);
    float2 vB0 = __half22float2(base[(size_t)b0 * 64 + lane]);
    float2 vB1 = __half22float2(base[(size_t)b1 * 64 + lane]);
    float2 vB2 = __half22float2(base[(size_t)b2 * 64 + lane]);
    float2 vB3 = __half22float2(base[(size_t)b3 * 64 + lane]);
    axA += vA0.x + vA2.x; ayA += vA0.y + vA2.y;
    bxA += vA1.x + vA3.x; byA += vA1.y + vA3.y;
    axB += vB0.x + vB2.x; ayB += vB0.y + vB2.y;
    bxB += vB1.x + vB3.x; byB += vB1.y + vB3.y;
    eA += 4; eB += 4;
  }

  // drain helper: 8-wide then scalar
  auto drain = [&](int e, int end, float& ax, float& ay, float& bx, float& by) {
    for (; e + 7 < end; e += 8) {
      int s[8];
      #pragma unroll
      for (int j = 0; j < 8; ++j) s[j] = csr[e + j];
      float2 v[8];
      #pragma unroll
      for (int j = 0; j < 8; ++j)
        v[j] = __half22float2(base[(size_t)s[j] * 64 + lane]);
      #pragma unroll
      for (int j = 0; j < 8; j += 4) {
        ax += v[j].x + v[j + 2].x;  ay += v[j].y + v[j + 2].y;
        bx += v[j + 1].x + v[j + 3].x;  by += v[j + 1].y + v[j + 3].y;
      }
    }
    for (; e < end; ++e) {
      int s = csr[e];
      float2 v = __half22float2(base[(size_t)s * 64 + lane]);
      ax += v.x; ay += v.y;
    }
  };
  drain(eA, endA, axA, ayA, bxA, byA);
  if (hasB) drain(eB, endB, axB, ayB, bxB, byB);

  float bx0 = bias[2 * lane], bx1 = bias[2 * lane + 1];
  {
    float dn = dinv[nA];
    float rx = fmaf(axA + bxA, dn, bx0);
    float ry = fmaf(ayA + byA, dn, bx1);
    ((__half2*)out)[(size_t)nA * 64 + lane] =
        __floats2half2_rn(fmaxf(rx, 0.f), fmaxf(ry, 0.f));
  }
  if (hasB) {
    float dn = dinv[nB];
    float rx = fmaf(axB + bxB, dn, bx0);
    float ry = fmaf(ayB + byB, dn, bx1);
    ((__half2*)out)[(size_t)nB * 64 + lane] =
        __floats2half2_rn(fmaxf(rx, 0.f), fmaxf(ry, 0.f));
  }
}

// ---------------------------------------------------------------------------
// Pool + graph boundaries (batch sorted)
// ---------------------------------------------------------------------------
__global__ __launch_bounds__(128) void k_pool(
    const __half* __restrict__ h, const int* __restrict__ batch,
    float* __restrict__ gsum, int* __restrict__ gstart,
    int* __restrict__ gend, int N) {
  int ch = threadIdx.x;
  int n0 = blockIdx.x * 128;
  int n1 = n0 + 128; if (n1 > N) n1 = N;
  if (n0 >= N) return;
  for (int n = n0 + ch; n < n1; n += 128) {
    int g = batch[n];
    if (n == 0 || batch[n - 1] != g) gstart[g] = n;
    if (n == N - 1 || batch[n + 1] != g) gend[g] = n + 1;
  }
  float acc = 0.f;
  int curg = batch[n0];
  for (int n = n0; n < n1; ++n) {
    int g = batch[n];
    if (g != curg) {
      atomicAdd(&gsum[curg * CH + ch], acc);
      acc = 0.f; curg = g;
    }
    acc += __half2float(h[(size_t)n * CH + ch]);
  }
  atomicAdd(&gsum[curg * CH + ch], acc);
}

// ---------------------------------------------------------------------------
// FC
// ---------------------------------------------------------------------------
__global__ __launch_bounds__(64) void k_fc(
    const float* __restrict__ gsum, const int* __restrict__ gstart,
    const int* __restrict__ gend, const float* __restrict__ Wfc,
    const float* __restrict__ bfc, float* __restrict__ outp) {
  int g = blockIdx.x;
  int j = threadIdx.x;
  if (j >= NCLS) return;
  int cnt = gend[g] - gstart[g];
  float invc = 1.0f / fmaxf((float)cnt, 1.0f);
  float acc = 0.0f;
  for (int c = 0; c < CH; ++c)
    acc = fmaf(gsum[g * CH + c], Wfc[c * NCLS + j], acc);
  outp[g * NCLS + j] = fmaf(acc, invc, bfc[j]);
}

// ---------------------------------------------------------------------------
extern "C" void kernel_launch(void* const* d_in, const int* in_sizes, int n_in,
                              void* d_out, int out_size, void* d_ws, size_t ws_size,
                              hipStream_t stream) {
  const float* x    = (const float*)d_in[0];
  const int*   ei   = (const int*)d_in[1];
  const int*   batch= (const int*)d_in[2];
  const float* W1   = (const float*)d_in[3];
  const float* b1   = (const float*)d_in[4];
  const float* W2   = (const float*)d_in[5];
  const float* b2   = (const float*)d_in[6];
  const float* Wfc  = (const float*)d_in[7];
  const float* bfc  = (const float*)d_in[8];
  float* outp = (float*)d_out;

  const int N = in_sizes[0] / CH;       // 100000
  const int E = in_sizes[1] / 2;        // 3200000
  const int* src = ei;
  const int* dst = ei + E;
  const int NBUCK = (N + BW - 1) >> BSHIFT;   // 196
  // Over-allocated bucket capacity: mean + ~18 sigma (Binomial), fill-safe.
  const int CAP = (E / NBUCK) + (E / NBUCK) / 8 + 256;

  // Workspace carve (256B aligned). First three buffers zeroed by ONE memset.
  char* w = (char*)d_ws;
  size_t o = 0;
  auto carve = [&](size_t bytes) -> void* {
    o = (o + 255) & ~(size_t)255;
    void* p = w + o;
    o += bytes;
    return p;
  };
  float*    gsum   = (float*)   carve((size_t)NGRAPH * CH * 4);  // zeroed
  int*      gstart = (int*)     carve((size_t)NGRAPH * 4);       // zeroed
  int*      gend   = (int*)     carve((size_t)NGRAPH * 4);       // zeroed
  size_t zbytes = o;
  int*      offs   = (int*)     carve((size_t)N * 4);
  int*      oendb  = (int*)     carve((size_t)N * 4);
  int*      gcur   = (int*)     carve(MAXB * 4);
  int*      csr    = (int*)     carve((size_t)NBUCK * CAP * 4);
  float*    dinv   = (float*)   carve((size_t)N * 4);
  _Float16* WhT1   = (_Float16*)carve((size_t)CH * CH * 2);
  _Float16* WhT2   = (_Float16*)carve((size_t)CH * CH * 2);
  __half*   xsbuf  = (__half*)  carve((size_t)N * CH * 2);  // fp16 gather buffer
  __half*   hbuf   = (__half*)  carve((size_t)N * CH * 2);  // fp16 h
  (void)ws_size;

  // ebuf (packed edges, gapped) aliases hbuf: NBUCK*CAP*4 ~ 14.6MB <= 25.6MB
  int* ebuf = (int*)hbuf;

  (void)hipMemsetAsync(gsum, 0, zbytes, stream);

  const int GB64 = (N + 63) / 64;       // 1563
  const int GB   = (N + 127) / 128;
  const int AB   = (N + 7) / 8;         // 2 nodes/wave, 4 waves/block

  k_init_wt<<<129, 256, 0, stream>>>(gcur, CAP, NBUCK, W1, W2, WhT1, WhT2);
  k_scatter<<<(E + 8191) / 8192, 1024, 0, stream>>>(src, dst, gcur, ebuf, E);
  k_build  <<<NBUCK, 1024, 0, stream>>>(ebuf, gcur, offs, oendb, dinv, csr, N, CAP);

  // Layer 1: xs = fp16((x@W1)*dinv) ; h = fp16(relu(agg(xs)*dinv + b1))
  k_gemm_f32<<<GB64, 256, 0, stream>>>(x, WhT1, dinv, xsbuf, N);
  k_agg<<<AB, 256, 0, stream>>>(xsbuf, csr, offs, oendb, dinv, b1, hbuf, N);
  // Layer 2
  k_gemm_f16<<<GB64, 256, 0, stream>>>((const _Float16*)hbuf, WhT2, dinv, xsbuf, N);
  k_agg<<<AB, 256, 0, stream>>>(xsbuf, csr, offs, oendb, dinv, b2, hbuf, N);

  // Pool (+ boundaries) + FC
  k_pool<<<GB, 128, 0, stream>>>(hbuf, batch, gsum, gstart, gend, N);
  k_fc<<<NGRAPH, 64, 0, stream>>>(gsum, gstart, gend, Wfc, bfc, outp);
  (void)out_size; (void)n_in;
}